// Round 3
// baseline (386.415 us; speedup 1.0000x reference)
//
#include <hip/hip_runtime.h>
#include <math.h>

// ---------------------------------------------------------------------------
// Sinkhorn ETP (FASTopic) on MI355X.
// n=256 topics, m=32768 words, D=384.
//
//   log_K0[i,j] = G[i,j] + su0[i] + sv0[j],  G = 40 * x@y^T
//   Per iteration:  L1[j] = lse_i(G+su);  W[j] = log_b - L1[j]
//                   L2[i] = lse_j(G+W);   su'[i] = log_a - L2[i]  (+su0 absorbed)
//   Final: transp[i,j] = exp(G+su[i]+W[j]); M = nx[i]+ny[j]-0.05*G;
//          loss = sum(transp*M)
//
// R8: E-reuse fast path (iters 2..100): exp(G+su+W) = E_ij * (b/S_j),
// E = exp(G+su-M_j), S_j = col sum. Row sums >= a*b for t>=2 -> plain sums.
//
// R9/R10 (failed): VGPR cap raise, then inline-asm tile pin. Pin provably
// kept the tile resident (AGPRs) yet dur/FETCH/VALUBusy all unchanged ->
// "per-pass G reload" theory dead. sink_step: 72us with VALU ~3us, HBM
// ~2.7us, LDS-conflicts nil -> 95% stall, cause unknown; its structural twin
// sink_fast runs ~2.4us on the same data.
//
// R11 (ablation by substitution): rebuild iter-1 on the sink_fast template,
// log-safe: tile = raw G in regs (pinned), 4 passes (colmax, colexpsum -> W
// [bitwise-identical to old], rowmax R, rowexpsum), ONE shared 17KB LDS
// combine buffer reused sequentially (LDS 40KB -> 24KB). Cross-block lse
// combine kept verbatim. Exact lse -> handles e^-400 orphan rows.
// Predicted: if structural, sink_step2 = 3-8us, total ~320us. If still
// ~70us, cause is first-reader-after-gemm cache state -> R12 fuses the
// column pass into gemm's epilogue.
// ---------------------------------------------------------------------------

#define N_TOPIC 256
#define N_WORD  32768

static constexpr float LOG_A = -5.545177444479562f;    // log(1/256 + 1e-30)
static constexpr float LOG_B = -10.397207708399179f;   // log(1/32768 + 1e-30)
static constexpr float BVAL  = 3.0517578125e-05f;      // 1/32768

typedef float f32x4 __attribute__((ext_vector_type(4)));
typedef short bf16x8 __attribute__((ext_vector_type(8)));

// Keep a float4's lanes pinned in VGPRs: empty asm is an opaque use+def, so
// the compiler cannot re-materialize the global load that produced them.
#define PIN4(v) asm volatile("" : "+v"((v).x), "+v"((v).y), "+v"((v).z), "+v"((v).w))

// ---------------------------------------------------------------- init ------
__global__ __launch_bounds__(256) void init_k(
    const float* __restrict__ x, const float* __restrict__ y,
    float* __restrict__ nx, float* __restrict__ ny, float* __restrict__ su,
    unsigned* __restrict__ colerr, int* __restrict__ active,
    int* __restrict__ counters, float* __restrict__ out)
{
    const int b = blockIdx.x, t = threadIdx.x;
    const int w = t >> 6, l = t & 63;
    if (b < 8192) {                       // ||y_j||^2, 4 rows/block (wave per row)
        const int r = (b << 2) + w;
        const float4* y4 = (const float4*)y;
        float4 v = y4[r * 96 + l];
        float s = v.x * v.x + v.y * v.y + v.z * v.z + v.w * v.w;
        if (l < 32) {
            float4 u = y4[r * 96 + 64 + l];
            s += u.x * u.x + u.y * u.y + u.z * u.z + u.w * u.w;
        }
        for (int off = 32; off; off >>= 1) s += __shfl_down(s, off);
        if (l == 0) ny[r] = s;
    } else if (b < 8256) {                // ||x_i||^2 and su0 = -20*nx
        const int r = ((b - 8192) << 2) + w;
        const float4* x4 = (const float4*)x;
        float4 v = x4[r * 96 + l];
        float s = v.x * v.x + v.y * v.y + v.z * v.z + v.w * v.w;
        if (l < 32) {
            float4 u = x4[r * 96 + 64 + l];
            s += u.x * u.x + u.y * u.y + u.z * u.z + u.w * u.w;
        }
        for (int off = 32; off; off >>= 1) s += __shfl_down(s, off);
        if (l == 0) { nx[r] = s; su[r] = -20.f * s; }
    } else {
        for (int k = t; k < 4096; k += 256) counters[k] = 0;
        if (t == 0) { colerr[0] = 0u; colerr[1] = 0u; active[0] = 1; out[0] = 0.f; }
    }
}

// ---------------------------------------------------------------- gemm ------
// Exact 3-way bf16 truncation split: v = b0 + b1 + b2 (+ r3, |r3|<=2^-27|v|).
static __device__ __forceinline__ void split3(float v, ushort& h0, ushort& h1, ushort& h2)
{
    unsigned u0 = __float_as_uint(v);
    h0 = (ushort)(u0 >> 16);
    float r1 = v - __uint_as_float(u0 & 0xFFFF0000u);
    unsigned u1 = __float_as_uint(r1);
    h1 = (ushort)(u1 >> 16);
    float r2 = r1 - __uint_as_float(u1 & 0xFFFF0000u);
    h2 = (ushort)(__float_as_uint(r2) >> 16);
}

// Block tile 128i x 128j, K-chunks of 32, grid (256 jb, 2 ib) = 512 blocks.
// Frag layouts (m89/m91-verified); y is [j][k] row-major = B^T identical frag.
__global__ __launch_bounds__(256, 1) void gemm_k(
    const float* __restrict__ x, const float* __restrict__ y, float* __restrict__ G)
{
    __shared__ __align__(16) ushort xs0[5120], xs1[5120], xs2[5120];
    __shared__ __align__(16) ushort ys0[5120], ys1[5120], ys2[5120];

    const int t   = threadIdx.x;
    const int jb  = blockIdx.x << 7;   // 128-col slab
    const int ib  = blockIdx.y << 7;   // 128-row slab
    const int w   = t >> 6;            // wave 0..3
    const int ln  = t & 63;
    const int q   = ln >> 4;           // quad 0..3
    const int l15 = ln & 15;

    const float4* x4 = (const float4*)x;
    const float4* y4 = (const float4*)y;

    f32x4 acc[2][8];
#pragma unroll
    for (int mi = 0; mi < 2; ++mi)
#pragma unroll
        for (int nj = 0; nj < 8; ++nj) acc[mi][nj] = (f32x4){0.f, 0.f, 0.f, 0.f};

    for (int kc = 0; kc < 12; ++kc) {
        __syncthreads();
#pragma unroll
        for (int p = 0; p < 4; ++p) {
            const int f  = (t << 2) + p;       // 0..1023 float4 slots
            const int r  = f >> 3, c4 = f & 7; // row, k-quad
            const int o  = r * 40 + (c4 << 2);
            float4 vx = x4[(ib + r) * 96 + (kc << 3) + c4];
            ushort a0,a1,a2,b0,b1,b2,c0,c1,c2,d0,d1,d2;
            split3(vx.x, a0,a1,a2); split3(vx.y, b0,b1,b2);
            split3(vx.z, c0,c1,c2); split3(vx.w, d0,d1,d2);
            *(ushort4*)&xs0[o] = make_ushort4(a0,b0,c0,d0);
            *(ushort4*)&xs1[o] = make_ushort4(a1,b1,c1,d1);
            *(ushort4*)&xs2[o] = make_ushort4(a2,b2,c2,d2);
            float4 vy = y4[(jb + r) * 96 + (kc << 3) + c4];
            split3(vy.x, a0,a1,a2); split3(vy.y, b0,b1,b2);
            split3(vy.z, c0,c1,c2); split3(vy.w, d0,d1,d2);
            *(ushort4*)&ys0[o] = make_ushort4(a0,b0,c0,d0);
            *(ushort4*)&ys1[o] = make_ushort4(a1,b1,c1,d1);
            *(ushort4*)&ys2[o] = make_ushort4(a2,b2,c2,d2);
        }
        __syncthreads();

        bf16x8 A[3][2];
#pragma unroll
        for (int mi = 0; mi < 2; ++mi) {
            const int off = ((w << 5) + (mi << 4) + l15) * 40 + (q << 3);
            A[0][mi] = *(const bf16x8*)&xs0[off];
            A[1][mi] = *(const bf16x8*)&xs1[off];
            A[2][mi] = *(const bf16x8*)&xs2[off];
        }
#pragma unroll
        for (int nj = 0; nj < 8; ++nj) {
            const int off = ((nj << 4) + l15) * 40 + (q << 3);
            bf16x8 B0 = *(const bf16x8*)&ys0[off];
            bf16x8 B1 = *(const bf16x8*)&ys1[off];
            bf16x8 B2 = *(const bf16x8*)&ys2[off];
#pragma unroll
            for (int mi = 0; mi < 2; ++mi) {
                f32x4 c = acc[mi][nj];
                c = __builtin_amdgcn_mfma_f32_16x16x32_bf16(A[0][mi], B0, c, 0, 0, 0);
                c = __builtin_amdgcn_mfma_f32_16x16x32_bf16(A[0][mi], B1, c, 0, 0, 0);
                c = __builtin_amdgcn_mfma_f32_16x16x32_bf16(A[1][mi], B0, c, 0, 0, 0);
                c = __builtin_amdgcn_mfma_f32_16x16x32_bf16(A[1][mi], B1, c, 0, 0, 0);
                c = __builtin_amdgcn_mfma_f32_16x16x32_bf16(A[0][mi], B2, c, 0, 0, 0);
                c = __builtin_amdgcn_mfma_f32_16x16x32_bf16(A[2][mi], B0, c, 0, 0, 0);
                acc[mi][nj] = c;
            }
        }
    }
#pragma unroll
    for (int mi = 0; mi < 2; ++mi) {
        const int gi0 = ib + (w << 5) + (mi << 4) + (q << 2);
#pragma unroll
        for (int nj = 0; nj < 8; ++nj) {
            const int gj = jb + (nj << 4) + l15;
#pragma unroll
            for (int r = 0; r < 4; ++r)
                G[(size_t)(gi0 + r) * 32768 + gj] = 40.f * acc[mi][nj][r];
        }
    }
}

// -------------------------------------------- iteration 1 (log-safe) --------
// R11: sink_fast-shaped, exact-lse kernel. tile = raw G (pinned); passes:
//   1) colmax M_j over (G+su)      2) colexpsum -> W_j (bitwise == old)
//   3) rowmax R_i over (G+W)       4) rowexpsum s_i = sum exp(G+W-R)
// One shared r_arr buffer reused for (3) and (4); cross-block lse combine
// identical to the old sink_step.
__global__ __launch_bounds__(256, 2) void sink_step2(
    const float* __restrict__ G, float* __restrict__ su,
    float* __restrict__ W, float2* __restrict__ pms, float2* __restrict__ lms,
    int* __restrict__ cnt)
{
    __shared__ float su_lds[256];
    __shared__ float comb[1024];
    __shared__ float Mlds[64];
    __shared__ float Wlds[64];
    __shared__ float Rlds[256];
    __shared__ float r_arr[256 * 17];
    __shared__ int lastf;

    const int t  = threadIdx.x;
    const int b  = blockIdx.x;
    const int j0 = b << 6;
    const int jq = t & 15;
    const int is = t >> 4;

    su_lds[t] = su[t];
    __syncthreads();

    const float4* G4 = (const float4*)G;
    float4 tile[16];
#pragma unroll
    for (int k = 0; k < 16; ++k) {
        int i = is + (k << 4);
        tile[k] = G4[i * 8192 + (j0 >> 2) + jq];
    }
#pragma unroll
    for (int k = 0; k < 16; ++k) PIN4(tile[k]);

    // ---- pass 1: column max of (G+su) over i ----
    float m0 = -INFINITY, m1 = -INFINITY, m2 = -INFINITY, m3 = -INFINITY;
#pragma unroll
    for (int k = 0; k < 16; ++k) {
        float sk = su_lds[is + (k << 4)];
        m0 = fmaxf(m0, tile[k].x + sk);
        m1 = fmaxf(m1, tile[k].y + sk);
        m2 = fmaxf(m2, tile[k].z + sk);
        m3 = fmaxf(m3, tile[k].w + sk);
    }
    ((float4*)comb)[(is << 4) + jq] = make_float4(m0, m1, m2, m3);
    __syncthreads();
    if (t < 64) {
        float m = -INFINITY;
#pragma unroll
        for (int s = 0; s < 16; ++s) m = fmaxf(m, comb[(s << 6) + t]);
        Mlds[t] = m;
    }
    __syncthreads();
    float4 Mq = make_float4(Mlds[4 * jq + 0], Mlds[4 * jq + 1],
                            Mlds[4 * jq + 2], Mlds[4 * jq + 3]);

    // ---- pass 2: column expsum -> W_j ----
    float s0 = 0.f, s1 = 0.f, s2 = 0.f, s3 = 0.f;
#pragma unroll
    for (int k = 0; k < 16; ++k) {
        float sk = su_lds[is + (k << 4)];
        s0 += __expf(tile[k].x + sk - Mq.x);
        s1 += __expf(tile[k].y + sk - Mq.y);
        s2 += __expf(tile[k].z + sk - Mq.z);
        s3 += __expf(tile[k].w + sk - Mq.w);
    }
    ((float4*)comb)[(is << 4) + jq] = make_float4(s0, s1, s2, s3);
    __syncthreads();
    if (t < 64) {
        float ssum = 0.f;
#pragma unroll
        for (int s = 0; s < 16; ++s) ssum += comb[(s << 6) + t];
        float Wj = LOG_B - (Mlds[t] + __logf(ssum));
        Wlds[t] = Wj;
        W[j0 + t] = Wj;
    }
    __syncthreads();
    float4 Wq = make_float4(Wlds[4 * jq + 0], Wlds[4 * jq + 1],
                            Wlds[4 * jq + 2], Wlds[4 * jq + 3]);

    // ---- pass 3: row max of (G+W) over this block's 64 j ----
#pragma unroll
    for (int k = 0; k < 16; ++k) {
        float a0 = tile[k].x + Wq.x;
        float a1 = tile[k].y + Wq.y;
        float a2 = tile[k].z + Wq.z;
        float a3 = tile[k].w + Wq.w;
        r_arr[(is + (k << 4)) * 17 + jq] = fmaxf(fmaxf(a0, a1), fmaxf(a2, a3));
    }
    __syncthreads();
    {
        float R = -INFINITY;
#pragma unroll
        for (int p = 0; p < 16; ++p) R = fmaxf(R, r_arr[t * 17 + p]);
        Rlds[t] = R;
    }
    __syncthreads();

    // ---- pass 4: row expsum vs R ----
#pragma unroll
    for (int k = 0; k < 16; ++k) {
        float Rr = Rlds[is + (k << 4)];
        float s = __expf(tile[k].x + Wq.x - Rr) + __expf(tile[k].y + Wq.y - Rr) +
                  __expf(tile[k].z + Wq.z - Rr) + __expf(tile[k].w + Wq.w - Rr);
        r_arr[(is + (k << 4)) * 17 + jq] = s;
    }
    __syncthreads();
    {
        float s = 0.f;
#pragma unroll
        for (int p = 0; p < 16; ++p) s += r_arr[t * 17 + p];
        pms[(b << 8) + t] = make_float2(Rlds[t], s);
    }

    // ---- two-level cross-block lse combine (verbatim from old sink_step) ----
    __threadfence();
    if (t == 0) lastf = (atomicAdd(cnt + (b >> 4), 1) == 15);
    __syncthreads();
    if (!lastf) return;
    __threadfence();

    const int g = b >> 4;
    {
        float cm[4] = {-INFINITY, -INFINITY, -INFINITY, -INFINITY};
        float cs[4] = {0.f, 0.f, 0.f, 0.f};
#pragma unroll
        for (int p = 0; p < 16; p += 4) {
#pragma unroll
            for (int c = 0; c < 4; ++c) {
                float2 v = pms[(((g << 4) + p + c) << 8) + t];
                float nm = fmaxf(cm[c], v.x);
                cs[c] = cs[c] * __expf(cm[c] - nm) + v.y * __expf(v.x - nm);
                cm[c] = nm;
            }
        }
        float m = cm[0], s = cs[0];
#pragma unroll
        for (int c = 1; c < 4; ++c) {
            float nm = fmaxf(m, cm[c]);
            s = s * __expf(m - nm) + cs[c] * __expf(cm[c] - nm);
            m = nm;
        }
        lms[(g << 8) + t] = make_float2(m, s);
    }

    __threadfence();
    if (t == 0) lastf = (atomicAdd(cnt + 32, 1) == 31);
    __syncthreads();
    if (!lastf) return;
    __threadfence();

    {
        float cm[4] = {-INFINITY, -INFINITY, -INFINITY, -INFINITY};
        float cs[4] = {0.f, 0.f, 0.f, 0.f};
#pragma unroll
        for (int p = 0; p < 32; p += 4) {
#pragma unroll
            for (int c = 0; c < 4; ++c) {
                float2 v = lms[((p + c) << 8) + t];
                float nm = fmaxf(cm[c], v.x);
                cs[c] = cs[c] * __expf(cm[c] - nm) + v.y * __expf(v.x - nm);
                cm[c] = nm;
            }
        }
        float m = cm[0], s = cs[0];
#pragma unroll
        for (int c = 1; c < 4; ++c) {
            float nm = fmaxf(m, cm[c]);
            s = s * __expf(m - nm) + cs[c] * __expf(cm[c] - nm);
            m = nm;
        }
        su[t] = LOG_A - (m + __logf(s));
    }
}

// -------------------------------------------- iteration (fast, 2..100) ------
// E-reuse: tile := exp((G+su) - M_j) after the column pass; phase R is one
// fma/elem vs 1/S_j; cross-block combine = plain sums (row sums >= a*b).
// su'[i] = LOG_A - LOG_B + su[i] - log(tot_i), tot_i = sum_j E_ij / S_j.
__global__ __launch_bounds__(256, 2) void sink_fast(
    const float* __restrict__ G, float* __restrict__ su,
    float* __restrict__ W, float* __restrict__ prow, float* __restrict__ lrow,
    int* __restrict__ cnt, const int* __restrict__ active)
{
    if (active[0] == 0) return;
    __shared__ float su_lds[256];
    __shared__ float comb[1024];
    __shared__ float Mlds[64];
    __shared__ float ecol[64];
    __shared__ float s_arr[256 * 17];
    __shared__ int lastf;

    const int t  = threadIdx.x;
    const int b  = blockIdx.x;
    const int j0 = b << 6;
    const int jq = t & 15;
    const int is = t >> 4;

    su_lds[t] = su[t];
    __syncthreads();

    const float4* G4 = (const float4*)G;
    float4 tile[16];
#pragma unroll
    for (int k = 0; k < 16; ++k) {
        int i = is + (k << 4);
        float4 g = G4[i * 8192 + (j0 >> 2) + jq];
        float s = su_lds[i];
        tile[k] = make_float4(g.x + s, g.y + s, g.z + s, g.w + s);
    }
#pragma unroll
    for (int k = 0; k < 16; ++k) PIN4(tile[k]);

    // column max over i
    float m0 = -INFINITY, m1 = -INFINITY, m2 = -INFINITY, m3 = -INFINITY;
#pragma unroll
    for (int k = 0; k < 16; ++k) {
        m0 = fmaxf(m0, tile[k].x);
        m1 = fmaxf(m1, tile[k].y);
        m2 = fmaxf(m2, tile[k].z);
        m3 = fmaxf(m3, tile[k].w);
    }
    ((float4*)comb)[(is << 4) + jq] = make_float4(m0, m1, m2, m3);
    __syncthreads();
    if (t < 64) {
        float m = -INFINITY;
#pragma unroll
        for (int s = 0; s < 16; ++s) m = fmaxf(m, comb[(s << 6) + t]);
        Mlds[t] = m;
    }
    __syncthreads();
    float4 Mq = make_float4(Mlds[4 * jq + 0], Mlds[4 * jq + 1],
                            Mlds[4 * jq + 2], Mlds[4 * jq + 3]);

    // E = exp(tile - M), column sums S
    float s0 = 0.f, s1 = 0.f, s2 = 0.f, s3 = 0.f;
#pragma unroll
    for (int k = 0; k < 16; ++k) {
        tile[k].x = __expf(tile[k].x - Mq.x); s0 += tile[k].x;
        tile[k].y = __expf(tile[k].y - Mq.y); s1 += tile[k].y;
        tile[k].z = __expf(tile[k].z - Mq.z); s2 += tile[k].z;
        tile[k].w = __expf(tile[k].w - Mq.w); s3 += tile[k].w;
    }
    ((float4*)comb)[(is << 4) + jq] = make_float4(s0, s1, s2, s3);
    __syncthreads();
    if (t < 64) {
        float ssum = 0.f;
#pragma unroll
        for (int s = 0; s < 16; ++s) ssum += comb[(s << 6) + t];
        W[j0 + t] = LOG_B - (Mlds[t] + __logf(ssum));
        ecol[t]   = 1.0f / ssum;            // = exp(W+M)/b
    }
    __syncthreads();
    float4 Eq = make_float4(ecol[4 * jq + 0], ecol[4 * jq + 1],
                            ecol[4 * jq + 2], ecol[4 * jq + 3]);

    // phase R: row partial = dot(E_rowslice, 1/S)
#pragma unroll
    for (int k = 0; k < 16; ++k) {
        float r = tile[k].x * Eq.x + tile[k].y * Eq.y +
                  tile[k].z * Eq.z + tile[k].w * Eq.w;
        s_arr[(is + (k << 4)) * 17 + jq] = r;
    }
    __syncthreads();
    {
        float s = 0.f;
#pragma unroll
        for (int p = 0; p < 16; ++p) s += s_arr[t * 17 + p];
        prow[(b << 8) + t] = s;
    }

    // two-level plain-sum combine
    __threadfence();
    if (t == 0) lastf = (atomicAdd(cnt + (b >> 4), 1) == 15);
    __syncthreads();
    if (!lastf) return;
    __threadfence();

    const int g = b >> 4;
    {
        float acc = 0.f;
#pragma unroll
        for (int p = 0; p < 16; ++p) acc += prow[(((g << 4) + p) << 8) + t];
        lrow[(g << 8) + t] = acc;
    }
    __threadfence();
    if (t == 0) lastf = (atomicAdd(cnt + 32, 1) == 31);
    __syncthreads();
    if (!lastf) return;
    __threadfence();
    {
        float tot = 0.f;
#pragma unroll
        for (int p = 0; p < 32; ++p) tot += lrow[(p << 8) + t];
        su[t] = (LOG_A - LOG_B) + su_lds[t] - __logf(tot);
    }
}

// --------------------------------------------- absorb-step column error -----
__global__ __launch_bounds__(256, 2) void sink_colerr(
    const float* __restrict__ G, const float* __restrict__ su,
    const float* __restrict__ W, unsigned* __restrict__ colerr, int slot,
    int* __restrict__ counter, int* __restrict__ active, int gated)
{
    if (gated && active[0] == 0) return;
    __shared__ float su_lds[256];
    __shared__ float comb[1024];
    __shared__ float Mlds[64];

    const int t  = threadIdx.x;
    const int b  = blockIdx.x;
    const int j0 = b << 6;
    const int jq = t & 15;
    const int is = t >> 4;

    su_lds[t] = su[t];
    __syncthreads();

    const float4* G4 = (const float4*)G;
    float4 tile[16];
#pragma unroll
    for (int k = 0; k < 16; ++k) {
        int i = is + (k << 4);
        tile[k] = G4[i * 8192 + (j0 >> 2) + jq];
    }
#pragma unroll
    for (int k = 0; k < 16; ++k) PIN4(tile[k]);

    float m0 = -INFINITY, m1 = -INFINITY, m2 = -INFINITY, m3 = -INFINITY;
#pragma unroll
    for (int k = 0; k < 16; ++k) {
        float sk = su_lds[is + (k << 4)];
        m0 = fmaxf(m0, tile[k].x + sk);
        m1 = fmaxf(m1, tile[k].y + sk);
        m2 = fmaxf(m2, tile[k].z + sk);
        m3 = fmaxf(m3, tile[k].w + sk);
    }
    ((float4*)comb)[(is << 4) + jq] = make_float4(m0, m1, m2, m3);
    __syncthreads();
    if (t < 64) {
        float m = -INFINITY;
#pragma unroll
        for (int s = 0; s < 16; ++s) m = fmaxf(m, comb[(s << 6) + t]);
        Mlds[t] = m;
    }
    __syncthreads();
    float4 Mq = make_float4(Mlds[4 * jq + 0], Mlds[4 * jq + 1],
                            Mlds[4 * jq + 2], Mlds[4 * jq + 3]);
    float s0 = 0.f, s1 = 0.f, s2 = 0.f, s3 = 0.f;
#pragma unroll
    for (int k = 0; k < 16; ++k) {
        float sk = su_lds[is + (k << 4)];
        s0 += __expf(tile[k].x + sk - Mq.x);
        s1 += __expf(tile[k].y + sk - Mq.y);
        s2 += __expf(tile[k].z + sk - Mq.z);
        s3 += __expf(tile[k].w + sk - Mq.w);
    }
    ((float4*)comb)[(is << 4) + jq] = make_float4(s0, s1, s2, s3);
    __syncthreads();
    if (t < 64) {
        float ssum = 0.f;
#pragma unroll
        for (int s = 0; s < 16; ++s) ssum += comb[(s << 6) + t];
        float Aj  = Mlds[t] + __logf(ssum);
        float col = __expf(Aj + W[j0 + t]);
        float d   = fabsf(col - BVAL);
        for (int off = 32; off; off >>= 1) d = fmaxf(d, __shfl_down(d, off));
        if (t == 0) {
            atomicMax(colerr + slot, __float_as_uint(d));
            __threadfence();
            if (atomicAdd(counter, 1) == 511) {
                __threadfence();
                unsigned e = atomicMax(colerr + slot, 0u);
                active[0] = (__uint_as_float(e) > 0.005f) ? 1 : 0;
            }
        }
    }
}

// ------------------------------------------------------------- finalize -----
__global__ __launch_bounds__(256) void finalize_k(
    const float* __restrict__ G, const float* __restrict__ su,
    const float* __restrict__ W, const float* __restrict__ nx,
    const float* __restrict__ ny, float* __restrict__ out)
{
    __shared__ float su_lds[256], nx_lds[256];
    __shared__ float red[4];
    const int t = threadIdx.x, b = blockIdx.x;
    const int j0 = b << 7;
    const int jq = t & 31;
    const int ig = t >> 5;
    su_lds[t] = su[t];
    nx_lds[t] = nx[t];
    __syncthreads();

    const float4* G4 = (const float4*)G;
    const float4 Wq  = ((const float4*)W)[(j0 >> 2) + jq];
    const float4 nyq = ((const float4*)ny)[(j0 >> 2) + jq];
    const int jbase = 1 + j0 + (jq << 2);
    float acc = 0.f;
#pragma unroll 4
    for (int it = 0; it < 32; ++it) {
        const int i = ig + (it << 3);
        float4 g = G4[i * 8192 + (j0 >> 2) + jq];
        const float si = su_lds[i], nxi = nx_lds[i];
        float v0 = __expf(g.x + si + Wq.x);
        float v1 = __expf(g.y + si + Wq.y);
        float v2 = __expf(g.z + si + Wq.z);
        float v3 = __expf(g.w + si + Wq.w);
        float* o = out + jbase + (size_t)i * 32768;
        o[0] = v0; o[1] = v1; o[2] = v2; o[3] = v3;
        acc += v0 * (nxi + nyq.x - 0.05f * g.x) +
               v1 * (nxi + nyq.y - 0.05f * g.y) +
               v2 * (nxi + nyq.z - 0.05f * g.z) +
               v3 * (nxi + nyq.w - 0.05f * g.w);
    }
    for (int off = 32; off; off >>= 1) acc += __shfl_down(acc, off);
    if ((t & 63) == 0) red[t >> 6] = acc;
    __syncthreads();
    if (t == 0) atomicAdd(out, red[0] + red[1] + red[2] + red[3]);
}

// ---------------------------------------------------------------- host ------
extern "C" void kernel_launch(void* const* d_in, const int* in_sizes, int n_in,
                              void* d_out, int out_size, void* d_ws, size_t ws_size,
                              hipStream_t stream)
{
    const float* x = (const float*)d_in[0];   // [256, 384]
    const float* y = (const float*)d_in[1];   // [32768, 384]
    float* out = (float*)d_out;               // [1 + 256*32768]

    float* ws   = (float*)d_ws;
    float* G    = ws;                 // 8388608
    float* Wv   = G + 8388608;        // 32768
    float* su   = Wv + 32768;         // 256
    float* nx   = su + 256;           // 256
    float* ny   = nx + 256;           // 32768
    float2* pms = (float2*)(ny + 32768);           // 131072 float2 (iter 1)
    float2* lms = pms + 131072;                    // 8192 float2
    float* prow = (float*)(lms + 8192);            // 131072 (iters 2+)
    float* lrow = prow + 131072;                   // 8192
    unsigned* colerr = (unsigned*)(lrow + 8192);   // 2
    int* active   = (int*)(colerr + 2);            // 1
    int* counters = active + 1;                    // 4096

    init_k<<<8257, 256, 0, stream>>>(x, y, nx, ny, su, colerr, active, counters, out);
    gemm_k<<<dim3(256, 2), 256, 0, stream>>>(x, y, G);

    // iteration 1 (log-safe, fast-structure) + absorb error check
    sink_step2<<<512, 256, 0, stream>>>(G, su, Wv, pms, lms, counters + 0);
    sink_colerr<<<512, 256, 0, stream>>>(G, su, Wv, colerr, 0, counters + 4000, active, 0);

    for (int tt = 2; tt <= 100; ++tt) {
        sink_fast<<<512, 256, 0, stream>>>(G, su, Wv, prow, lrow,
                                           counters + 40 * (tt - 1), active);
        if (tt == 51)   // absorb at cpt_n=51: error check gates the rest
            sink_colerr<<<512, 256, 0, stream>>>(G, su, Wv, colerr, 1,
                                                 counters + 4001, active, 1);
    }

    finalize_k<<<256, 256, 0, stream>>>(G, su, Wv, nx, ny, out);
}

// Round 4
// 382.902 us; speedup vs baseline: 1.0092x; 1.0092x over previous
//
#include <hip/hip_runtime.h>
#include <math.h>

// ---------------------------------------------------------------------------
// Sinkhorn ETP (FASTopic) on MI355X.
// n=256 topics, m=32768 words, D=384.
//
//   log_K0[i,j] = G[i,j] + su0[i] + sv0[j],  G = 40 * x@y^T
//   Per iteration:  L1[j] = lse_i(G+su);  W[j] = log_b - L1[j]
//                   L2[i] = lse_j(G+W);   su'[i] = log_a - L2[i]  (+su0 absorbed)
//   Final: transp[i,j] = exp(G+su[i]+W[j]); M = nx[i]+ny[j]-0.05*G;
//          loss = sum(transp*M)
//
// R8: E-reuse fast path (iters 2..100). R9/R10 (failed): VGPR cap, reg pin.
// R11 (ablation): iter-1 rebuilt on the sink_fast template -> STILL 75us
// while sink_fast = ~2.4us on the same data; sink_colerr (2nd reader, same
// pattern) is fast every round. Structure fully exonerated; the cost is
// POSITIONAL: first reader of G after gemm_k.
//
// R12 theory: gemm_k leaves ~32MB of G dirty across the 8 non-coherent
// per-XCD L2s (8 x 4MB = exactly G's size). The inter-kernel release/acquire
// must write back + invalidate that dirty data before the next kernel's
// reads are legal; the drain lands in sink_step2's dispatch window = ~70us
// of all-pipes-idle stall. Fix: gemm_k writes G with nontemporal stores
// (evict-first -> writeback streams out DURING gemm), same for finalize_k's
// 32MB out write (drains in the timed tail otherwise).
// Predicted: sink_step2 75 -> <=10us, FETCH 17 -> ~26-32MB, VALUBusy >12%;
// total ~300-325us. Falsifier: unchanged -> theory dies, R13 does the
// toucher test + cooperative persistent-loop rewrite.
// ---------------------------------------------------------------------------

#define N_TOPIC 256
#define N_WORD  32768

static constexpr float LOG_A = -5.545177444479562f;    // log(1/256 + 1e-30)
static constexpr float LOG_B = -10.397207708399179f;   // log(1/32768 + 1e-30)
static constexpr float BVAL  = 3.0517578125e-05f;      // 1/32768

typedef float f32x4 __attribute__((ext_vector_type(4)));
typedef short bf16x8 __attribute__((ext_vector_type(8)));

// Keep a float4's lanes pinned in VGPRs: empty asm is an opaque use+def, so
// the compiler cannot re-materialize the global load that produced them.
#define PIN4(v) asm volatile("" : "+v"((v).x), "+v"((v).y), "+v"((v).z), "+v"((v).w))

// ---------------------------------------------------------------- init ------
__global__ __launch_bounds__(256) void init_k(
    const float* __restrict__ x, const float* __restrict__ y,
    float* __restrict__ nx, float* __restrict__ ny, float* __restrict__ su,
    unsigned* __restrict__ colerr, int* __restrict__ active,
    int* __restrict__ counters, float* __restrict__ out)
{
    const int b = blockIdx.x, t = threadIdx.x;
    const int w = t >> 6, l = t & 63;
    if (b < 8192) {                       // ||y_j||^2, 4 rows/block (wave per row)
        const int r = (b << 2) + w;
        const float4* y4 = (const float4*)y;
        float4 v = y4[r * 96 + l];
        float s = v.x * v.x + v.y * v.y + v.z * v.z + v.w * v.w;
        if (l < 32) {
            float4 u = y4[r * 96 + 64 + l];
            s += u.x * u.x + u.y * u.y + u.z * u.z + u.w * u.w;
        }
        for (int off = 32; off; off >>= 1) s += __shfl_down(s, off);
        if (l == 0) ny[r] = s;
    } else if (b < 8256) {                // ||x_i||^2 and su0 = -20*nx
        const int r = ((b - 8192) << 2) + w;
        const float4* x4 = (const float4*)x;
        float4 v = x4[r * 96 + l];
        float s = v.x * v.x + v.y * v.y + v.z * v.z + v.w * v.w;
        if (l < 32) {
            float4 u = x4[r * 96 + 64 + l];
            s += u.x * u.x + u.y * u.y + u.z * u.z + u.w * u.w;
        }
        for (int off = 32; off; off >>= 1) s += __shfl_down(s, off);
        if (l == 0) { nx[r] = s; su[r] = -20.f * s; }
    } else {
        for (int k = t; k < 4096; k += 256) counters[k] = 0;
        if (t == 0) { colerr[0] = 0u; colerr[1] = 0u; active[0] = 1; out[0] = 0.f; }
    }
}

// ---------------------------------------------------------------- gemm ------
// Exact 3-way bf16 truncation split: v = b0 + b1 + b2 (+ r3, |r3|<=2^-27|v|).
static __device__ __forceinline__ void split3(float v, ushort& h0, ushort& h1, ushort& h2)
{
    unsigned u0 = __float_as_uint(v);
    h0 = (ushort)(u0 >> 16);
    float r1 = v - __uint_as_float(u0 & 0xFFFF0000u);
    unsigned u1 = __float_as_uint(r1);
    h1 = (ushort)(u1 >> 16);
    float r2 = r1 - __uint_as_float(u1 & 0xFFFF0000u);
    h2 = (ushort)(__float_as_uint(r2) >> 16);
}

// Block tile 128i x 128j, K-chunks of 32, grid (256 jb, 2 ib) = 512 blocks.
// Frag layouts (m89/m91-verified); y is [j][k] row-major = B^T identical frag.
// R12: C-write uses nontemporal stores -> G's writeback overlaps gemm
// execution instead of draining at the next kernel's acquire.
__global__ __launch_bounds__(256, 1) void gemm_k(
    const float* __restrict__ x, const float* __restrict__ y, float* __restrict__ G)
{
    __shared__ __align__(16) ushort xs0[5120], xs1[5120], xs2[5120];
    __shared__ __align__(16) ushort ys0[5120], ys1[5120], ys2[5120];

    const int t   = threadIdx.x;
    const int jb  = blockIdx.x << 7;   // 128-col slab
    const int ib  = blockIdx.y << 7;   // 128-row slab
    const int w   = t >> 6;            // wave 0..3
    const int ln  = t & 63;
    const int q   = ln >> 4;           // quad 0..3
    const int l15 = ln & 15;

    const float4* x4 = (const float4*)x;
    const float4* y4 = (const float4*)y;

    f32x4 acc[2][8];
#pragma unroll
    for (int mi = 0; mi < 2; ++mi)
#pragma unroll
        for (int nj = 0; nj < 8; ++nj) acc[mi][nj] = (f32x4){0.f, 0.f, 0.f, 0.f};

    for (int kc = 0; kc < 12; ++kc) {
        __syncthreads();
#pragma unroll
        for (int p = 0; p < 4; ++p) {
            const int f  = (t << 2) + p;       // 0..1023 float4 slots
            const int r  = f >> 3, c4 = f & 7; // row, k-quad
            const int o  = r * 40 + (c4 << 2);
            float4 vx = x4[(ib + r) * 96 + (kc << 3) + c4];
            ushort a0,a1,a2,b0,b1,b2,c0,c1,c2,d0,d1,d2;
            split3(vx.x, a0,a1,a2); split3(vx.y, b0,b1,b2);
            split3(vx.z, c0,c1,c2); split3(vx.w, d0,d1,d2);
            *(ushort4*)&xs0[o] = make_ushort4(a0,b0,c0,d0);
            *(ushort4*)&xs1[o] = make_ushort4(a1,b1,c1,d1);
            *(ushort4*)&xs2[o] = make_ushort4(a2,b2,c2,d2);
            float4 vy = y4[(jb + r) * 96 + (kc << 3) + c4];
            split3(vy.x, a0,a1,a2); split3(vy.y, b0,b1,b2);
            split3(vy.z, c0,c1,c2); split3(vy.w, d0,d1,d2);
            *(ushort4*)&ys0[o] = make_ushort4(a0,b0,c0,d0);
            *(ushort4*)&ys1[o] = make_ushort4(a1,b1,c1,d1);
            *(ushort4*)&ys2[o] = make_ushort4(a2,b2,c2,d2);
        }
        __syncthreads();

        bf16x8 A[3][2];
#pragma unroll
        for (int mi = 0; mi < 2; ++mi) {
            const int off = ((w << 5) + (mi << 4) + l15) * 40 + (q << 3);
            A[0][mi] = *(const bf16x8*)&xs0[off];
            A[1][mi] = *(const bf16x8*)&xs1[off];
            A[2][mi] = *(const bf16x8*)&xs2[off];
        }
#pragma unroll
        for (int nj = 0; nj < 8; ++nj) {
            const int off = ((nj << 4) + l15) * 40 + (q << 3);
            bf16x8 B0 = *(const bf16x8*)&ys0[off];
            bf16x8 B1 = *(const bf16x8*)&ys1[off];
            bf16x8 B2 = *(const bf16x8*)&ys2[off];
#pragma unroll
            for (int mi = 0; mi < 2; ++mi) {
                f32x4 c = acc[mi][nj];
                c = __builtin_amdgcn_mfma_f32_16x16x32_bf16(A[0][mi], B0, c, 0, 0, 0);
                c = __builtin_amdgcn_mfma_f32_16x16x32_bf16(A[0][mi], B1, c, 0, 0, 0);
                c = __builtin_amdgcn_mfma_f32_16x16x32_bf16(A[1][mi], B0, c, 0, 0, 0);
                c = __builtin_amdgcn_mfma_f32_16x16x32_bf16(A[1][mi], B1, c, 0, 0, 0);
                c = __builtin_amdgcn_mfma_f32_16x16x32_bf16(A[0][mi], B2, c, 0, 0, 0);
                c = __builtin_amdgcn_mfma_f32_16x16x32_bf16(A[2][mi], B0, c, 0, 0, 0);
                acc[mi][nj] = c;
            }
        }
    }
#pragma unroll
    for (int mi = 0; mi < 2; ++mi) {
        const int gi0 = ib + (w << 5) + (mi << 4) + (q << 2);
#pragma unroll
        for (int nj = 0; nj < 8; ++nj) {
            const int gj = jb + (nj << 4) + l15;
#pragma unroll
            for (int r = 0; r < 4; ++r)
                __builtin_nontemporal_store(40.f * acc[mi][nj][r],
                                            &G[(size_t)(gi0 + r) * 32768 + gj]);
        }
    }
}

// -------------------------------------------- iteration 1 (log-safe) --------
// R11: sink_fast-shaped, exact-lse kernel. tile = raw G (pinned); passes:
//   1) colmax M_j over (G+su)      2) colexpsum -> W_j
//   3) rowmax R_i over (G+W)       4) rowexpsum s_i = sum exp(G+W-R)
// One shared r_arr buffer reused for (3) and (4); cross-block lse combine.
__global__ __launch_bounds__(256, 2) void sink_step2(
    const float* __restrict__ G, float* __restrict__ su,
    float* __restrict__ W, float2* __restrict__ pms, float2* __restrict__ lms,
    int* __restrict__ cnt)
{
    __shared__ float su_lds[256];
    __shared__ float comb[1024];
    __shared__ float Mlds[64];
    __shared__ float Wlds[64];
    __shared__ float Rlds[256];
    __shared__ float r_arr[256 * 17];
    __shared__ int lastf;

    const int t  = threadIdx.x;
    const int b  = blockIdx.x;
    const int j0 = b << 6;
    const int jq = t & 15;
    const int is = t >> 4;

    su_lds[t] = su[t];
    __syncthreads();

    const float4* G4 = (const float4*)G;
    float4 tile[16];
#pragma unroll
    for (int k = 0; k < 16; ++k) {
        int i = is + (k << 4);
        tile[k] = G4[i * 8192 + (j0 >> 2) + jq];
    }
#pragma unroll
    for (int k = 0; k < 16; ++k) PIN4(tile[k]);

    // ---- pass 1: column max of (G+su) over i ----
    float m0 = -INFINITY, m1 = -INFINITY, m2 = -INFINITY, m3 = -INFINITY;
#pragma unroll
    for (int k = 0; k < 16; ++k) {
        float sk = su_lds[is + (k << 4)];
        m0 = fmaxf(m0, tile[k].x + sk);
        m1 = fmaxf(m1, tile[k].y + sk);
        m2 = fmaxf(m2, tile[k].z + sk);
        m3 = fmaxf(m3, tile[k].w + sk);
    }
    ((float4*)comb)[(is << 4) + jq] = make_float4(m0, m1, m2, m3);
    __syncthreads();
    if (t < 64) {
        float m = -INFINITY;
#pragma unroll
        for (int s = 0; s < 16; ++s) m = fmaxf(m, comb[(s << 6) + t]);
        Mlds[t] = m;
    }
    __syncthreads();
    float4 Mq = make_float4(Mlds[4 * jq + 0], Mlds[4 * jq + 1],
                            Mlds[4 * jq + 2], Mlds[4 * jq + 3]);

    // ---- pass 2: column expsum -> W_j ----
    float s0 = 0.f, s1 = 0.f, s2 = 0.f, s3 = 0.f;
#pragma unroll
    for (int k = 0; k < 16; ++k) {
        float sk = su_lds[is + (k << 4)];
        s0 += __expf(tile[k].x + sk - Mq.x);
        s1 += __expf(tile[k].y + sk - Mq.y);
        s2 += __expf(tile[k].z + sk - Mq.z);
        s3 += __expf(tile[k].w + sk - Mq.w);
    }
    ((float4*)comb)[(is << 4) + jq] = make_float4(s0, s1, s2, s3);
    __syncthreads();
    if (t < 64) {
        float ssum = 0.f;
#pragma unroll
        for (int s = 0; s < 16; ++s) ssum += comb[(s << 6) + t];
        float Wj = LOG_B - (Mlds[t] + __logf(ssum));
        Wlds[t] = Wj;
        W[j0 + t] = Wj;
    }
    __syncthreads();
    float4 Wq = make_float4(Wlds[4 * jq + 0], Wlds[4 * jq + 1],
                            Wlds[4 * jq + 2], Wlds[4 * jq + 3]);

    // ---- pass 3: row max of (G+W) over this block's 64 j ----
#pragma unroll
    for (int k = 0; k < 16; ++k) {
        float a0 = tile[k].x + Wq.x;
        float a1 = tile[k].y + Wq.y;
        float a2 = tile[k].z + Wq.z;
        float a3 = tile[k].w + Wq.w;
        r_arr[(is + (k << 4)) * 17 + jq] = fmaxf(fmaxf(a0, a1), fmaxf(a2, a3));
    }
    __syncthreads();
    {
        float R = -INFINITY;
#pragma unroll
        for (int p = 0; p < 16; ++p) R = fmaxf(R, r_arr[t * 17 + p]);
        Rlds[t] = R;
    }
    __syncthreads();

    // ---- pass 4: row expsum vs R ----
#pragma unroll
    for (int k = 0; k < 16; ++k) {
        float Rr = Rlds[is + (k << 4)];
        float s = __expf(tile[k].x + Wq.x - Rr) + __expf(tile[k].y + Wq.y - Rr) +
                  __expf(tile[k].z + Wq.z - Rr) + __expf(tile[k].w + Wq.w - Rr);
        r_arr[(is + (k << 4)) * 17 + jq] = s;
    }
    __syncthreads();
    {
        float s = 0.f;
#pragma unroll
        for (int p = 0; p < 16; ++p) s += r_arr[t * 17 + p];
        pms[(b << 8) + t] = make_float2(Rlds[t], s);
    }

    // ---- two-level cross-block lse combine ----
    __threadfence();
    if (t == 0) lastf = (atomicAdd(cnt + (b >> 4), 1) == 15);
    __syncthreads();
    if (!lastf) return;
    __threadfence();

    const int g = b >> 4;
    {
        float cm[4] = {-INFINITY, -INFINITY, -INFINITY, -INFINITY};
        float cs[4] = {0.f, 0.f, 0.f, 0.f};
#pragma unroll
        for (int p = 0; p < 16; p += 4) {
#pragma unroll
            for (int c = 0; c < 4; ++c) {
                float2 v = pms[(((g << 4) + p + c) << 8) + t];
                float nm = fmaxf(cm[c], v.x);
                cs[c] = cs[c] * __expf(cm[c] - nm) + v.y * __expf(v.x - nm);
                cm[c] = nm;
            }
        }
        float m = cm[0], s = cs[0];
#pragma unroll
        for (int c = 1; c < 4; ++c) {
            float nm = fmaxf(m, cm[c]);
            s = s * __expf(m - nm) + cs[c] * __expf(cm[c] - nm);
            m = nm;
        }
        lms[(g << 8) + t] = make_float2(m, s);
    }

    __threadfence();
    if (t == 0) lastf = (atomicAdd(cnt + 32, 1) == 31);
    __syncthreads();
    if (!lastf) return;
    __threadfence();

    {
        float cm[4] = {-INFINITY, -INFINITY, -INFINITY, -INFINITY};
        float cs[4] = {0.f, 0.f, 0.f, 0.f};
#pragma unroll
        for (int p = 0; p < 32; p += 4) {
#pragma unroll
            for (int c = 0; c < 4; ++c) {
                float2 v = lms[((p + c) << 8) + t];
                float nm = fmaxf(cm[c], v.x);
                cs[c] = cs[c] * __expf(cm[c] - nm) + v.y * __expf(v.x - nm);
                cm[c] = nm;
            }
        }
        float m = cm[0], s = cs[0];
#pragma unroll
        for (int c = 1; c < 4; ++c) {
            float nm = fmaxf(m, cm[c]);
            s = s * __expf(m - nm) + cs[c] * __expf(cm[c] - nm);
            m = nm;
        }
        su[t] = LOG_A - (m + __logf(s));
    }
}

// -------------------------------------------- iteration (fast, 2..100) ------
// E-reuse: tile := exp((G+su) - M_j) after the column pass; phase R is one
// fma/elem vs 1/S_j; cross-block combine = plain sums (row sums >= a*b).
// su'[i] = LOG_A - LOG_B + su[i] - log(tot_i), tot_i = sum_j E_ij / S_j.
__global__ __launch_bounds__(256, 2) void sink_fast(
    const float* __restrict__ G, float* __restrict__ su,
    float* __restrict__ W, float* __restrict__ prow, float* __restrict__ lrow,
    int* __restrict__ cnt, const int* __restrict__ active)
{
    if (active[0] == 0) return;
    __shared__ float su_lds[256];
    __shared__ float comb[1024];
    __shared__ float Mlds[64];
    __shared__ float ecol[64];
    __shared__ float s_arr[256 * 17];
    __shared__ int lastf;

    const int t  = threadIdx.x;
    const int b  = blockIdx.x;
    const int j0 = b << 6;
    const int jq = t & 15;
    const int is = t >> 4;

    su_lds[t] = su[t];
    __syncthreads();

    const float4* G4 = (const float4*)G;
    float4 tile[16];
#pragma unroll
    for (int k = 0; k < 16; ++k) {
        int i = is + (k << 4);
        float4 g = G4[i * 8192 + (j0 >> 2) + jq];
        float s = su_lds[i];
        tile[k] = make_float4(g.x + s, g.y + s, g.z + s, g.w + s);
    }
#pragma unroll
    for (int k = 0; k < 16; ++k) PIN4(tile[k]);

    // column max over i
    float m0 = -INFINITY, m1 = -INFINITY, m2 = -INFINITY, m3 = -INFINITY;
#pragma unroll
    for (int k = 0; k < 16; ++k) {
        m0 = fmaxf(m0, tile[k].x);
        m1 = fmaxf(m1, tile[k].y);
        m2 = fmaxf(m2, tile[k].z);
        m3 = fmaxf(m3, tile[k].w);
    }
    ((float4*)comb)[(is << 4) + jq] = make_float4(m0, m1, m2, m3);
    __syncthreads();
    if (t < 64) {
        float m = -INFINITY;
#pragma unroll
        for (int s = 0; s < 16; ++s) m = fmaxf(m, comb[(s << 6) + t]);
        Mlds[t] = m;
    }
    __syncthreads();
    float4 Mq = make_float4(Mlds[4 * jq + 0], Mlds[4 * jq + 1],
                            Mlds[4 * jq + 2], Mlds[4 * jq + 3]);

    // E = exp(tile - M), column sums S
    float s0 = 0.f, s1 = 0.f, s2 = 0.f, s3 = 0.f;
#pragma unroll
    for (int k = 0; k < 16; ++k) {
        tile[k].x = __expf(tile[k].x - Mq.x); s0 += tile[k].x;
        tile[k].y = __expf(tile[k].y - Mq.y); s1 += tile[k].y;
        tile[k].z = __expf(tile[k].z - Mq.z); s2 += tile[k].z;
        tile[k].w = __expf(tile[k].w - Mq.w); s3 += tile[k].w;
    }
    ((float4*)comb)[(is << 4) + jq] = make_float4(s0, s1, s2, s3);
    __syncthreads();
    if (t < 64) {
        float ssum = 0.f;
#pragma unroll
        for (int s = 0; s < 16; ++s) ssum += comb[(s << 6) + t];
        W[j0 + t] = LOG_B - (Mlds[t] + __logf(ssum));
        ecol[t]   = 1.0f / ssum;            // = exp(W+M)/b
    }
    __syncthreads();
    float4 Eq = make_float4(ecol[4 * jq + 0], ecol[4 * jq + 1],
                            ecol[4 * jq + 2], ecol[4 * jq + 3]);

    // phase R: row partial = dot(E_rowslice, 1/S)
#pragma unroll
    for (int k = 0; k < 16; ++k) {
        float r = tile[k].x * Eq.x + tile[k].y * Eq.y +
                  tile[k].z * Eq.z + tile[k].w * Eq.w;
        s_arr[(is + (k << 4)) * 17 + jq] = r;
    }
    __syncthreads();
    {
        float s = 0.f;
#pragma unroll
        for (int p = 0; p < 16; ++p) s += s_arr[t * 17 + p];
        prow[(b << 8) + t] = s;
    }

    // two-level plain-sum combine
    __threadfence();
    if (t == 0) lastf = (atomicAdd(cnt + (b >> 4), 1) == 15);
    __syncthreads();
    if (!lastf) return;
    __threadfence();

    const int g = b >> 4;
    {
        float acc = 0.f;
#pragma unroll
        for (int p = 0; p < 16; ++p) acc += prow[(((g << 4) + p) << 8) + t];
        lrow[(g << 8) + t] = acc;
    }
    __threadfence();
    if (t == 0) lastf = (atomicAdd(cnt + 32, 1) == 31);
    __syncthreads();
    if (!lastf) return;
    __threadfence();
    {
        float tot = 0.f;
#pragma unroll
        for (int p = 0; p < 32; ++p) tot += lrow[(p << 8) + t];
        su[t] = (LOG_A - LOG_B) + su_lds[t] - __logf(tot);
    }
}

// --------------------------------------------- absorb-step column error -----
__global__ __launch_bounds__(256, 2) void sink_colerr(
    const float* __restrict__ G, const float* __restrict__ su,
    const float* __restrict__ W, unsigned* __restrict__ colerr, int slot,
    int* __restrict__ counter, int* __restrict__ active, int gated)
{
    if (gated && active[0] == 0) return;
    __shared__ float su_lds[256];
    __shared__ float comb[1024];
    __shared__ float Mlds[64];

    const int t  = threadIdx.x;
    const int b  = blockIdx.x;
    const int j0 = b << 6;
    const int jq = t & 15;
    const int is = t >> 4;

    su_lds[t] = su[t];
    __syncthreads();

    const float4* G4 = (const float4*)G;
    float4 tile[16];
#pragma unroll
    for (int k = 0; k < 16; ++k) {
        int i = is + (k << 4);
        tile[k] = G4[i * 8192 + (j0 >> 2) + jq];
    }
#pragma unroll
    for (int k = 0; k < 16; ++k) PIN4(tile[k]);

    float m0 = -INFINITY, m1 = -INFINITY, m2 = -INFINITY, m3 = -INFINITY;
#pragma unroll
    for (int k = 0; k < 16; ++k) {
        float sk = su_lds[is + (k << 4)];
        m0 = fmaxf(m0, tile[k].x + sk);
        m1 = fmaxf(m1, tile[k].y + sk);
        m2 = fmaxf(m2, tile[k].z + sk);
        m3 = fmaxf(m3, tile[k].w + sk);
    }
    ((float4*)comb)[(is << 4) + jq] = make_float4(m0, m1, m2, m3);
    __syncthreads();
    if (t < 64) {
        float m = -INFINITY;
#pragma unroll
        for (int s = 0; s < 16; ++s) m = fmaxf(m, comb[(s << 6) + t]);
        Mlds[t] = m;
    }
    __syncthreads();
    float4 Mq = make_float4(Mlds[4 * jq + 0], Mlds[4 * jq + 1],
                            Mlds[4 * jq + 2], Mlds[4 * jq + 3]);
    float s0 = 0.f, s1 = 0.f, s2 = 0.f, s3 = 0.f;
#pragma unroll
    for (int k = 0; k < 16; ++k) {
        float sk = su_lds[is + (k << 4)];
        s0 += __expf(tile[k].x + sk - Mq.x);
        s1 += __expf(tile[k].y + sk - Mq.y);
        s2 += __expf(tile[k].z + sk - Mq.z);
        s3 += __expf(tile[k].w + sk - Mq.w);
    }
    ((float4*)comb)[(is << 4) + jq] = make_float4(s0, s1, s2, s3);
    __syncthreads();
    if (t < 64) {
        float ssum = 0.f;
#pragma unroll
        for (int s = 0; s < 16; ++s) ssum += comb[(s << 6) + t];
        float Aj  = Mlds[t] + __logf(ssum);
        float col = __expf(Aj + W[j0 + t]);
        float d   = fabsf(col - BVAL);
        for (int off = 32; off; off >>= 1) d = fmaxf(d, __shfl_down(d, off));
        if (t == 0) {
            atomicMax(colerr + slot, __float_as_uint(d));
            __threadfence();
            if (atomicAdd(counter, 1) == 511) {
                __threadfence();
                unsigned e = atomicMax(colerr + slot, 0u);
                active[0] = (__uint_as_float(e) > 0.005f) ? 1 : 0;
            }
        }
    }
}

// ------------------------------------------------------------- finalize -----
// R12: bulk transp writes are nontemporal (32MB; otherwise its dirty L2
// drains in the timed tail).
__global__ __launch_bounds__(256) void finalize_k(
    const float* __restrict__ G, const float* __restrict__ su,
    const float* __restrict__ W, const float* __restrict__ nx,
    const float* __restrict__ ny, float* __restrict__ out)
{
    __shared__ float su_lds[256], nx_lds[256];
    __shared__ float red[4];
    const int t = threadIdx.x, b = blockIdx.x;
    const int j0 = b << 7;
    const int jq = t & 31;
    const int ig = t >> 5;
    su_lds[t] = su[t];
    nx_lds[t] = nx[t];
    __syncthreads();

    const float4* G4 = (const float4*)G;
    const float4 Wq  = ((const float4*)W)[(j0 >> 2) + jq];
    const float4 nyq = ((const float4*)ny)[(j0 >> 2) + jq];
    const int jbase = 1 + j0 + (jq << 2);
    float acc = 0.f;
#pragma unroll 4
    for (int it = 0; it < 32; ++it) {
        const int i = ig + (it << 3);
        float4 g = G4[i * 8192 + (j0 >> 2) + jq];
        const float si = su_lds[i], nxi = nx_lds[i];
        float v0 = __expf(g.x + si + Wq.x);
        float v1 = __expf(g.y + si + Wq.y);
        float v2 = __expf(g.z + si + Wq.z);
        float v3 = __expf(g.w + si + Wq.w);
        float* o = out + jbase + (size_t)i * 32768;
        __builtin_nontemporal_store(v0, o + 0);
        __builtin_nontemporal_store(v1, o + 1);
        __builtin_nontemporal_store(v2, o + 2);
        __builtin_nontemporal_store(v3, o + 3);
        acc += v0 * (nxi + nyq.x - 0.05f * g.x) +
               v1 * (nxi + nyq.y - 0.05f * g.y) +
               v2 * (nxi + nyq.z - 0.05f * g.z) +
               v3 * (nxi + nyq.w - 0.05f * g.w);
    }
    for (int off = 32; off; off >>= 1) acc += __shfl_down(acc, off);
    if ((t & 63) == 0) red[t >> 6] = acc;
    __syncthreads();
    if (t == 0) atomicAdd(out, red[0] + red[1] + red[2] + red[3]);
}

// ---------------------------------------------------------------- host ------
extern "C" void kernel_launch(void* const* d_in, const int* in_sizes, int n_in,
                              void* d_out, int out_size, void* d_ws, size_t ws_size,
                              hipStream_t stream)
{
    const float* x = (const float*)d_in[0];   // [256, 384]
    const float* y = (const float*)d_in[1];   // [32768, 384]
    float* out = (float*)d_out;               // [1 + 256*32768]

    float* ws   = (float*)d_ws;
    float* G    = ws;                 // 8388608
    float* Wv   = G + 8388608;        // 32768
    float* su   = Wv + 32768;         // 256
    float* nx   = su + 256;           // 256
    float* ny   = nx + 256;           // 32768
    float2* pms = (float2*)(ny + 32768);           // 131072 float2 (iter 1)
    float2* lms = pms + 131072;                    // 8192 float2
    float* prow = (float*)(lms + 8192);            // 131072 (iters 2+)
    float* lrow = prow + 131072;                   // 8192
    unsigned* colerr = (unsigned*)(lrow + 8192);   // 2
    int* active   = (int*)(colerr + 2);            // 1
    int* counters = active + 1;                    // 4096

    init_k<<<8257, 256, 0, stream>>>(x, y, nx, ny, su, colerr, active, counters, out);
    gemm_k<<<dim3(256, 2), 256, 0, stream>>>(x, y, G);

    // iteration 1 (log-safe, fast-structure) + absorb error check
    sink_step2<<<512, 256, 0, stream>>>(G, su, Wv, pms, lms, counters + 0);
    sink_colerr<<<512, 256, 0, stream>>>(G, su, Wv, colerr, 0, counters + 4000, active, 0);

    for (int tt = 2; tt <= 100; ++tt) {
        sink_fast<<<512, 256, 0, stream>>>(G, su, Wv, prow, lrow,
                                           counters + 40 * (tt - 1), active);
        if (tt == 51)   // absorb at cpt_n=51: error check gates the rest
            sink_colerr<<<512, 256, 0, stream>>>(G, su, Wv, colerr, 1,
                                                 counters + 4001, active, 1);
    }

    finalize_k<<<256, 256, 0, stream>>>(G, su, Wv, nx, ny, out);
}